// Round 14
// baseline (1217.295 us; speedup 1.0000x reference)
//
#include <hip/hip_runtime.h>

#define NB_ 16
#define TQ_ 2048
#define TS_ 2048
#define DH_ 1024
#define QB_ 32
#define SB_ 256
#define NT_ 512

typedef _Float16 f16x8 __attribute__((ext_vector_type(8)));
typedef _Float16 f16x4 __attribute__((ext_vector_type(4)));
typedef float f32x4 __attribute__((ext_vector_type(4)));

__device__ inline uint32_t pack_h2(float a, float b) {
  union { _Float16 h[2]; uint32_t u; } c;
  c.h[0] = (_Float16)a; c.h[1] = (_Float16)b;
  return c.u;
}

// Prologue: enc f32 [b][s][h] -> encH f16 [b][s][h] AND encT f16 [b][h][s]  [v7-verified]
__global__ void conv_tr(const float* __restrict__ src,
                        _Float16* __restrict__ dH,
                        _Float16* __restrict__ dT) {
  const int b  = blockIdx.x;
  const int st = blockIdx.y;   // s-tile of 64
  const int ht = blockIdx.z;   // h-tile of 64
  const int tid = threadIdx.x;
  __shared__ _Float16 t[64][72];

  const size_t base = ((size_t)b * TS_ + (size_t)st * 64) * DH_ + (size_t)ht * 64;
  #pragma unroll
  for (int k = 0; k < 16; ++k) {
    int i = k * 256 + tid;
    int sl = i >> 6, hl = i & 63;
    float v = src[base + (size_t)sl * DH_ + hl];
    _Float16 h = (_Float16)v;
    dH[base + (size_t)sl * DH_ + hl] = h;
    t[sl][hl] = h;
  }
  __syncthreads();
  const size_t tbase = ((size_t)b * DH_ + (size_t)ht * 64) * TS_ + (size_t)st * 64;
  #pragma unroll
  for (int k = 0; k < 8; ++k) {
    int i = k * 256 + tid;
    int hl = i >> 5, s2 = (i & 31) * 2;
    union { _Float16 h[2]; uint32_t u; } pk;
    pk.h[0] = t[s2][hl];
    pk.h[1] = t[s2 + 1][hl];
    *(uint32_t*)((_Float16*)dT + tbase + (size_t)hl * TS_ + s2) = pk.u;
  }
}

__device__ inline f16x8 cvt8(const float* __restrict__ fp) {
  float4 a = *(const float4*)fp;
  float4 b = *(const float4*)(fp + 4);
  f16x8 t;
  t[0] = (_Float16)a.x; t[1] = (_Float16)a.y; t[2] = (_Float16)a.z; t[3] = (_Float16)a.w;
  t[4] = (_Float16)b.x; t[5] = (_Float16)b.y; t[6] = (_Float16)b.z; t[7] = (_Float16)b.w;
  return t;
}

// LDS layout (bytes), total 115584 (1 WG/CU):
//   q_base : 0      .. 65536   Q [32 q][1024 d] f16, byte=(q*2048+d*2)^((q&7)<<4)  [v12-verified]
//   s_lds  : 65536  .. 98816   S f32 [32 q][260]  (single-writer full S tile)      [v12-verified]
//   p_base : 98816  .. 115200  P [32 q][256 s] f16, byte=(q*512+s*2)^((q&7)<<4)    [v12-verified]
//   m/l/c  : 115200 .. 115584  softmax state
template<int MODE>   // 1 = encH+encT in ws; 0 = direct f32 fallback (correctness only)
__global__ __launch_bounds__(NT_, 2)
void attn_v14(const float* __restrict__ hid,
              const float* __restrict__ enc,
              const _Float16* __restrict__ encH,
              const _Float16* __restrict__ encT,
              float* __restrict__ out) {
  __shared__ __attribute__((aligned(16))) char smem[115584];
  char*  const q_base = smem;
  float* const s_lds  = (float*)(smem + 65536);
  char*  const p_base = smem + 98816;
  float* const m_lds  = (float*)(smem + 115200);
  float* const l_lds  = m_lds + 32;
  float* const c_lds  = m_lds + 64;

  const int tid  = threadIdx.x;
  const int lane = tid & 63;
  const int wid  = tid >> 6;
  const int arow = lane & 15;
  const int agrp = lane >> 4;

  // XCD-affine: XCD x sweeps all 64 q-tiles of batch x, then batch x+8.
  const int bi  = blockIdx.x;
  const int x   = bi & 7;
  const int idx = bi >> 3;
  const int b   = x + 8 * (idx >> 6);
  const int q0  = (idx & 63) * QB_;

  const int hw = wid;  // PV h-chunk (128 wide); QK^T s-chunk = wid*32

  if (tid < 32) { m_lds[tid] = -__builtin_inff(); l_lds[tid] = 0.0f; }

  // ---- stage Q (32 x 1024) fp32 -> f16 into LDS, swizzled (v12-verified) ----
  {
    const float* qsrc = hid + ((size_t)b * TQ_ + q0) * DH_;
    #pragma unroll
    for (int k = 0; k < 16; ++k) {
      int i = tid + k * NT_;
      int q = i >> 8;
      int h = (i & 255) * 4;
      float4 v = *(const float4*)(qsrc + (size_t)q * DH_ + h);
      int byte = (q * 2048 + h * 2) ^ ((q & 7) << 4);
      *(uint32_t*)(q_base + byte)     = pack_h2(v.x, v.y);
      *(uint32_t*)(q_base + byte + 4) = pack_h2(v.z, v.w);
    }
  }
  __syncthreads();

  f32x4 o_acc[2][8];   // [m][n] over 128 h  (64 AGPR persistent)
  #pragma unroll
  for (int m = 0; m < 2; ++m)
    #pragma unroll
    for (int n = 0; n < 8; ++n)
      o_acc[m][n] = {};

  const size_t enc_b  = (size_t)b * TS_ * DH_;
  const size_t encT_b = (size_t)b * DH_ * TS_;

  for (int st = 0; st < TS_ / SB_; ++st) {
    const int s0 = st * SB_;

    // ================= QK^T (v12-verified): full-d S[32q][32s], s-chunk = wid*32 =================
    f32x4 sacc[2][2] = {{{}, {}}, {{}, {}}};
    {
      const size_t krow = enc_b + (size_t)(s0 + wid * 32 + arow) * DH_;
      #pragma unroll
      for (int kf = 0; kf < 32; ++kf) {
        const int d = kf * 32 + agrp * 8;
        f16x8 bf0, bf1;
        if constexpr (MODE == 1) {
          bf0 = *(const f16x8*)(encH + krow + d);
          bf1 = *(const f16x8*)(encH + krow + (size_t)16 * DH_ + d);
        } else {
          bf0 = cvt8(enc + krow + d);
          bf1 = cvt8(enc + krow + (size_t)16 * DH_ + d);
        }
        f16x8 af0 = *(const f16x8*)(q_base + ((arow * 2048 + d * 2) ^ ((arow & 7) << 4)));
        f16x8 af1 = *(const f16x8*)(q_base + (((16 + arow) * 2048 + d * 2) ^ ((arow & 7) << 4)));
        sacc[0][0] = __builtin_amdgcn_mfma_f32_16x16x32_f16(af0, bf0, sacc[0][0], 0, 0, 0);
        sacc[0][1] = __builtin_amdgcn_mfma_f32_16x16x32_f16(af0, bf1, sacc[0][1], 0, 0, 0);
        sacc[1][0] = __builtin_amdgcn_mfma_f32_16x16x32_f16(af1, bf0, sacc[1][0], 0, 0, 0);
        sacc[1][1] = __builtin_amdgcn_mfma_f32_16x16x32_f16(af1, bf1, sacc[1][1], 0, 0, 0);
      }
    }

    // write S tile (single writer per element)
    {
      const int sc = wid * 32 + arow;
      #pragma unroll
      for (int m = 0; m < 2; ++m)
        #pragma unroll
        for (int n = 0; n < 2; ++n)
          #pragma unroll
          for (int i2 = 0; i2 < 4; ++i2)
            s_lds[(m * 16 + agrp * 4 + i2) * 260 + sc + n * 16] = sacc[m][n][i2];
    }

    __syncthreads();  // b1: S complete

    // ================= online softmax over [32 q][256 s] (v12-verified) =================
    {
      int q = tid >> 4, sq = tid & 15;
      const float* bp = s_lds + q * 260 + sq * 16;
      f32x4 v0 = *(const f32x4*)bp;
      f32x4 v1 = *(const f32x4*)(bp + 4);
      f32x4 v2 = *(const f32x4*)(bp + 8);
      f32x4 v3 = *(const f32x4*)(bp + 12);
      f32x4 vm = v0;
      #pragma unroll
      for (int j = 0; j < 4; ++j) { vm[j] = fmaxf(fmaxf(v0[j], v1[j]), fmaxf(v2[j], v3[j])); }
      float mx = fmaxf(fmaxf(vm[0], vm[1]), fmaxf(vm[2], vm[3]));
      #pragma unroll
      for (int o = 8; o; o >>= 1) mx = fmaxf(mx, __shfl_xor(mx, o));
      float mprev = m_lds[q];
      float mnew  = fmaxf(mprev, mx);
      float p[16], ps = 0.0f;
      #pragma unroll
      for (int j = 0; j < 4; ++j) {
        p[j]      = __expf(v0[j] - mnew);
        p[4 + j]  = __expf(v1[j] - mnew);
        p[8 + j]  = __expf(v2[j] - mnew);
        p[12 + j] = __expf(v3[j] - mnew);
      }
      #pragma unroll
      for (int j = 0; j < 16; ++j) ps += p[j];
      #pragma unroll
      for (int o = 8; o; o >>= 1) ps += __shfl_xor(ps, o);
      if (sq == 0) {
        float cf = __expf(mprev - mnew);
        m_lds[q] = mnew;
        l_lds[q] = l_lds[q] * cf + ps;
        c_lds[q] = cf;
      }
      #pragma unroll
      for (int g = 0; g < 4; ++g) {
        f16x4 pw;
        pw[0] = (_Float16)p[g * 4 + 0]; pw[1] = (_Float16)p[g * 4 + 1];
        pw[2] = (_Float16)p[g * 4 + 2]; pw[3] = (_Float16)p[g * 4 + 3];
        *(f16x4*)(p_base + ((q * 512 + sq * 32 + g * 8) ^ ((q & 7) << 4))) = pw;
      }
    }

    __syncthreads();  // b2: P + m/l/c complete

    // ---- rescale O ----
    #pragma unroll
    for (int m = 0; m < 2; ++m)
      #pragma unroll
      for (int i2 = 0; i2 < 4; ++i2) {
        float cf = c_lds[m * 16 + agrp * 4 + i2];
        #pragma unroll
        for (int n = 0; n < 8; ++n) o_acc[m][n][i2] *= cf;
      }

    // ================= PV: B-frags straight from encT (no LDS staging) =================
    // o[q][h] = sum_s P[q][s] * encT[h][s]; 8 ks-steps of 32 s, 8 n-subtiles of 16 h.
    #pragma unroll
    for (int ks = 0; ks < 8; ++ks) {
      f16x8 paf0 = *(const f16x8*)(p_base +
          ((arow * 512 + ks * 64 + agrp * 16) ^ ((arow & 7) << 4)));
      f16x8 paf1 = *(const f16x8*)(p_base +
          (((16 + arow) * 512 + ks * 64 + agrp * 16) ^ ((arow & 7) << 4)));
      __builtin_amdgcn_s_setprio(1);
      #pragma unroll
      for (int n = 0; n < 8; ++n) {
        const int hg = hw * 128 + n * 16 + arow;
        f16x8 bv;
        if constexpr (MODE == 1) {
          bv = *(const f16x8*)(encT + encT_b + (size_t)hg * TS_ + s0 + ks * 32 + agrp * 8);
        } else {
          #pragma unroll
          for (int j = 0; j < 8; ++j)
            bv[j] = (_Float16)enc[enc_b + (size_t)(s0 + ks * 32 + agrp * 8 + j) * DH_ + hg];
        }
        o_acc[0][n] = __builtin_amdgcn_mfma_f32_16x16x32_f16(paf0, bv, o_acc[0][n], 0, 0, 0);
        o_acc[1][n] = __builtin_amdgcn_mfma_f32_16x16x32_f16(paf1, bv, o_acc[1][n], 0, 0, 0);
      }
      __builtin_amdgcn_s_setprio(0);
    }
  }

  // ================= epilogue: O / l =================
  #pragma unroll
  for (int m = 0; m < 2; ++m) {
    #pragma unroll
    for (int i2 = 0; i2 < 4; ++i2) {
      int qr = m * 16 + agrp * 4 + i2;
      float inv = 1.0f / l_lds[qr];
      #pragma unroll
      for (int n = 0; n < 8; ++n) {
        out[((size_t)(b * TQ_ + q0 + qr)) * DH_ + hw * 128 + n * 16 + arow] =
            o_acc[m][n][i2] * inv;
      }
    }
  }
}

extern "C" void kernel_launch(void* const* d_in, const int* in_sizes, int n_in,
                              void* d_out, int out_size, void* d_ws, size_t ws_size,
                              hipStream_t stream) {
  (void)in_sizes; (void)n_in; (void)out_size;
  const float* hid = (const float*)d_in[0];
  const float* enc = (const float*)d_in[1];
  float* out = (float*)d_out;

  const size_t encN = (size_t)NB_ * TS_ * DH_;
  const bool ws_ok = (ws_size >= 2 * encN * sizeof(_Float16));  // encH + encT

  dim3 grid(NB_ * (TQ_ / QB_), 1, 1);
  dim3 block(NT_, 1, 1);

  if (ws_ok) {
    _Float16* encH = (_Float16*)d_ws;
    _Float16* encT = encH + encN;
    dim3 cgrid(NB_, TS_ / 64, DH_ / 64);
    conv_tr<<<cgrid, dim3(256), 0, stream>>>(enc, encH, encT);
    attn_v14<1><<<grid, block, 0, stream>>>(hid, enc, encH, encT, out);
  } else {
    attn_v14<0><<<grid, block, 0, stream>>>(hid, enc, nullptr, nullptr, out);
  }
}

// Round 15
// 930.615 us; speedup vs baseline: 1.3081x; 1.3081x over previous
//
#include <hip/hip_runtime.h>

#define NB_ 16
#define TQ_ 2048
#define TS_ 2048
#define DH_ 1024
#define QB_ 32
#define SB_ 512
#define NT_ 1024

typedef _Float16 f16x8 __attribute__((ext_vector_type(8)));
typedef float f32x4 __attribute__((ext_vector_type(4)));
typedef uint32_t u32x2 __attribute__((ext_vector_type(2)));

__device__ inline uint32_t pack_h2(float a, float b) {
  union { _Float16 h[2]; uint32_t u; } c;
  c.h[0] = (_Float16)a; c.h[1] = (_Float16)b;
  return c.u;
}

__global__ void convert_f32_f16(const float* __restrict__ src, _Float16* __restrict__ dst) {
  size_t i = ((size_t)blockIdx.x * blockDim.x + threadIdx.x) * 8;
  float4 v0 = *(const float4*)(src + i);
  float4 v1 = *(const float4*)(src + i + 4);
  f16x8 o;
  o[0] = (_Float16)v0.x; o[1] = (_Float16)v0.y; o[2] = (_Float16)v0.z; o[3] = (_Float16)v0.w;
  o[4] = (_Float16)v1.x; o[5] = (_Float16)v1.y; o[6] = (_Float16)v1.z; o[7] = (_Float16)v1.w;
  *(f16x8*)(dst + i) = o;
}

__device__ inline f16x8 cvt8(const float* __restrict__ fp) {
  float4 a = *(const float4*)fp;
  float4 b = *(const float4*)(fp + 4);
  f16x8 t;
  t[0] = (_Float16)a.x; t[1] = (_Float16)a.y; t[2] = (_Float16)a.z; t[3] = (_Float16)a.w;
  t[4] = (_Float16)b.x; t[5] = (_Float16)b.y; t[6] = (_Float16)b.z; t[7] = (_Float16)b.w;
  return t;
}

template<bool WS16>
__device__ inline f16x8 ld8(const _Float16* __restrict__ hp, const float* __restrict__ fp, size_t idx) {
  if constexpr (WS16) return *(const f16x8*)(hp + idx);
  else return cvt8(fp + idx);
}

// Vt swizzle: 2-way (free) on BOTH transposed b32 writes and b128 reads (bank-analyzed).
__device__ inline int vt_swz(int hl, int byte) {
  return byte ^ (((hl >> 1) & 3) << 4) ^ (((hl >> 3) & 1) << 6);
}

// LDS layout (bytes), total 135808 (1 WG/CU, 16 waves = 4/SIMD):
//   q_base : 0      .. 65536   Q [32 q][1024 d] f16, byte=(q*2048+d*2)^((q&7)<<4)  [verified]
//   p_lds  : 65536  .. 98304   P [32 q][512 s] f16, byte=(q*1024+s*2)^((q&7)<<4)   [v13-verified]
//   vt_all : 98304  .. 131072  16 x 2048 per-wave V-transpose [32 h][32 s], vt_swz
//   pmax   : 131072 .. 133184  [16 w][33] f32 partial max (pad 33)
//   lsum   : 133184 .. 135296  [16 w][33] f32 partial sum
//   mst    : 135296 .. 135552  [2][32] f32 running max (tile-parity)
//   lst    : 135552 .. 135808  [2][32] f32 running sum (tile-parity)
//   c_lds  : 135808 .. 135936  [32] f32 per-tile rescale
template<bool WS16>
__global__ __launch_bounds__(NT_, 4)
void attn_v15(const float* __restrict__ hid,
              const float* __restrict__ enc,
              const _Float16* __restrict__ encH,
              float* __restrict__ out) {
  __shared__ __attribute__((aligned(16))) char smem[135936];
  char*  const q_base = smem;
  char*  const p_lds  = smem + 65536;
  char*  const vt_all = smem + 98304;
  float* const pmax   = (float*)(smem + 131072);
  float* const lsum   = (float*)(smem + 133184);
  float* const mst    = (float*)(smem + 135296);
  float* const lst    = (float*)(smem + 135552);
  float* const c_lds  = (float*)(smem + 135808);

  const int tid  = threadIdx.x;
  const int lane = tid & 63;
  const int wid  = tid >> 6;         // 0..15
  const int arow = lane & 15;
  const int agrp = lane >> 4;

  // XCD-affine: XCD x sweeps all 64 q-tiles of batch x, then batch x+8.
  const int bi  = blockIdx.x;
  const int x   = bi & 7;
  const int idx = bi >> 3;
  const int b   = x + 8 * (idx >> 6);
  const int q0  = (idx & 63) * QB_;

  const int hw = wid;   // PV h-chunk (64 wide); QK^T s-chunk = wid*32

  if (tid < 32) { mst[tid] = -__builtin_inff(); lst[tid] = 0.0f; }

  // ---- stage Q (32 x 1024) fp32 -> f16 into LDS, swizzled (verified) ----
  {
    const float* qsrc = hid + ((size_t)b * TQ_ + q0) * DH_;
    #pragma unroll
    for (int k = 0; k < 8; ++k) {
      int i = tid + k * NT_;            // 8192 float4 units
      int q = i >> 8;
      int h = (i & 255) * 4;
      float4 v = *(const float4*)(qsrc + (size_t)q * DH_ + h);
      int byte = (q * 2048 + h * 2) ^ ((q & 7) << 4);
      *(uint32_t*)(q_base + byte)     = pack_h2(v.x, v.y);
      *(uint32_t*)(q_base + byte + 4) = pack_h2(v.z, v.w);
    }
  }
  __syncthreads();

  f32x4 o_acc[2][4];   // [m][hh*2+n] over 64 h  (32 AGPR persistent)
  #pragma unroll
  for (int m = 0; m < 2; ++m)
    #pragma unroll
    for (int j = 0; j < 4; ++j)
      o_acc[m][j] = {};

  char* const vt = vt_all + wid * 2048;
  const size_t enc_b = (size_t)b * TS_ * DH_;
  const int c8 = (lane & 3) * 8;        // V staging h-octet (within 32)
  const int d2 = (lane >> 2) * 2;       // V staging s-pair base (0..30)

  for (int st = 0; st < TS_ / SB_; ++st) {
    const int s0 = st * SB_;
    const int p  = st & 1;

    // ================= swapped QK^T: C[s][q], wave s-chunk = wid*32 =================
    f32x4 sacc[2][2];   // [t s-subtile][m q-subtile]
    #pragma unroll
    for (int t = 0; t < 2; ++t) { sacc[t][0] = {}; sacc[t][1] = {}; }
    {
      const size_t krow = enc_b + (size_t)(s0 + wid * 32 + arow) * DH_;
      #pragma unroll
      for (int kf = 0; kf < 32; ++kf) {
        const int d = kf * 32 + agrp * 8;
        f16x8 qf0 = *(const f16x8*)(q_base + ((arow * 2048 + d * 2) ^ ((arow & 7) << 4)));
        f16x8 qf1 = *(const f16x8*)(q_base + (((16 + arow) * 2048 + d * 2) ^ ((arow & 7) << 4)));
        f16x8 kf0 = ld8<WS16>(encH, enc, krow + d);
        f16x8 kf1 = ld8<WS16>(encH, enc, krow + (size_t)16 * DH_ + d);
        sacc[0][0] = __builtin_amdgcn_mfma_f32_16x16x32_f16(kf0, qf0, sacc[0][0], 0, 0, 0);
        sacc[0][1] = __builtin_amdgcn_mfma_f32_16x16x32_f16(kf0, qf1, sacc[0][1], 0, 0, 0);
        sacc[1][0] = __builtin_amdgcn_mfma_f32_16x16x32_f16(kf1, qf0, sacc[1][0], 0, 0, 0);
        sacc[1][1] = __builtin_amdgcn_mfma_f32_16x16x32_f16(kf1, qf1, sacc[1][1], 0, 0, 0);
      }
    }

    // ---- issue PV pass-0 V loads (complete during softmax) ----
    f16x8 stgA[2], stgB[2];
    {
      size_t base = enc_b + (size_t)(s0 + d2) * DH_ + hw * 64 + c8;
      stgA[0] = ld8<WS16>(encH, enc, base);
      stgA[1] = ld8<WS16>(encH, enc, base + DH_);
    }

    // ---- per-wave partial max (lane holds s rows, q = arow col) ----
    #pragma unroll
    for (int m = 0; m < 2; ++m) {
      float pm = sacc[0][m][0];
      #pragma unroll
      for (int t = 0; t < 2; ++t)
        #pragma unroll
        for (int i2 = 0; i2 < 4; ++i2) pm = fmaxf(pm, sacc[t][m][i2]);
      pm = fmaxf(pm, __shfl_xor(pm, 16));
      pm = fmaxf(pm, __shfl_xor(pm, 32));
      if (agrp == 0) pmax[wid * 33 + m * 16 + arow] = pm;
    }

    __syncthreads();  // b1: pmax complete

    float mnew[2], cfac[2];
    #pragma unroll
    for (int m = 0; m < 2; ++m) {
      const int q = m * 16 + arow;
      float mv = mst[p * 32 + q];
      const float mp = mv;
      #pragma unroll
      for (int w = 0; w < 16; ++w) mv = fmaxf(mv, pmax[w * 33 + q]);
      mnew[m] = mv;
      cfac[m] = __expf(mp - mv);
    }

    // exp, partial sums, pack P -> LDS (A-frag layout)
    #pragma unroll
    for (int m = 0; m < 2; ++m) {
      const int q = m * 16 + arow;
      float ls = 0.0f;
      #pragma unroll
      for (int t = 0; t < 2; ++t) {
        float e0 = __expf(sacc[t][m][0] - mnew[m]);
        float e1 = __expf(sacc[t][m][1] - mnew[m]);
        float e2 = __expf(sacc[t][m][2] - mnew[m]);
        float e3 = __expf(sacc[t][m][3] - mnew[m]);
        ls += (e0 + e1) + (e2 + e3);
        u32x2 pw;
        pw[0] = pack_h2(e0, e1);
        pw[1] = pack_h2(e2, e3);
        const int s_loc = wid * 32 + t * 16 + agrp * 4;
        *(u32x2*)(p_lds + ((q * 1024 + s_loc * 2) ^ ((q & 7) << 4))) = pw;
      }
      ls += __shfl_xor(ls, 16);
      ls += __shfl_xor(ls, 32);
      if (agrp == 0) lsum[wid * 33 + q] = ls;
    }

    if (wid == 0 && agrp == 0) {
      #pragma unroll
      for (int m = 0; m < 2; ++m) {
        const int q = m * 16 + arow;
        c_lds[q] = cfac[m];
        mst[(p ^ 1) * 32 + q] = mnew[m];
      }
    }

    __syncthreads();  // b2: P + lsum + c + mst complete

    // l update (wave 0; lsum was complete at b2)
    if (wid == 0 && agrp == 0) {
      #pragma unroll
      for (int m = 0; m < 2; ++m) {
        const int q = m * 16 + arow;
        float s16 = 0.0f;
        #pragma unroll
        for (int w = 0; w < 16; ++w) s16 += lsum[w * 33 + q];
        lst[(p ^ 1) * 32 + q] = lst[p * 32 + q] * cfac[m] + s16;
      }
    }

    // ---- rescale O ----
    #pragma unroll
    for (int m = 0; m < 2; ++m)
      #pragma unroll
      for (int i2 = 0; i2 < 4; ++i2) {
        float cf = c_lds[m * 16 + agrp * 4 + i2];
        #pragma unroll
        for (int j = 0; j < 4; ++j) o_acc[m][j][i2] *= cf;
      }

    // ================= PV: 16 s-phases x 2 h-halves; vt quantum [32h][32s] =================
    #pragma unroll
    for (int sp = 0; sp < 16; ++sp) {
      f16x8 paf0 = *(const f16x8*)(p_lds +
          ((arow * 1024 + sp * 64 + agrp * 16) ^ ((arow & 7) << 4)));
      f16x8 paf1 = *(const f16x8*)(p_lds +
          (((16 + arow) * 1024 + sp * 64 + agrp * 16) ^ ((arow & 7) << 4)));
      #pragma unroll
      for (int hh = 0; hh < 2; ++hh) {
        const int p2 = sp * 2 + hh;
        const bool useA = (p2 & 1) == 0;
        // write Vt (wave-private, DS in-order, no barrier)
        #pragma unroll
        for (int jj = 0; jj < 8; ++jj) {
          const int hl = c8 + jj;
          uint32_t u = useA ? pack_h2((float)stgA[0][jj], (float)stgA[1][jj])
                            : pack_h2((float)stgB[0][jj], (float)stgB[1][jj]);
          *(uint32_t*)(vt + vt_swz(hl, hl * 64 + d2 * 2)) = u;
        }
        // issue next pass's V loads into the other buffer
        if (p2 < 31) {
          const int spn = (p2 + 1) >> 1, hhn = (p2 + 1) & 1;
          size_t base = enc_b + (size_t)(s0 + spn * 32 + d2) * DH_ + hw * 64 + hhn * 32 + c8;
          if (useA) {
            stgB[0] = ld8<WS16>(encH, enc, base);
            stgB[1] = ld8<WS16>(encH, enc, base + DH_);
          } else {
            stgA[0] = ld8<WS16>(encH, enc, base);
            stgA[1] = ld8<WS16>(encH, enc, base + DH_);
          }
        }
        __builtin_amdgcn_s_setprio(1);
        #pragma unroll
        for (int n = 0; n < 2; ++n) {
          const int hl = n * 16 + arow;
          f16x8 bv = *(const f16x8*)(vt + vt_swz(hl, hl * 64 + agrp * 16));
          o_acc[0][hh * 2 + n] = __builtin_amdgcn_mfma_f32_16x16x32_f16(paf0, bv, o_acc[0][hh * 2 + n], 0, 0, 0);
          o_acc[1][hh * 2 + n] = __builtin_amdgcn_mfma_f32_16x16x32_f16(paf1, bv, o_acc[1][hh * 2 + n], 0, 0, 0);
        }
        __builtin_amdgcn_s_setprio(0);
      }
    }
  }

  __syncthreads();  // final l state (slot 0 after 4 tiles) visible

  // ================= epilogue: O / l =================
  #pragma unroll
  for (int m = 0; m < 2; ++m) {
    #pragma unroll
    for (int i2 = 0; i2 < 4; ++i2) {
      int qr = m * 16 + agrp * 4 + i2;
      float inv = 1.0f / lst[qr];   // slot 0
      #pragma unroll
      for (int j = 0; j < 4; ++j) {
        out[((size_t)(b * TQ_ + q0 + qr)) * DH_ + hw * 64 + (j >> 1) * 32 + (j & 1) * 16 + arow] =
            o_acc[m][j][i2] * inv;
      }
    }
  }
}

extern "C" void kernel_launch(void* const* d_in, const int* in_sizes, int n_in,
                              void* d_out, int out_size, void* d_ws, size_t ws_size,
                              hipStream_t stream) {
  (void)in_sizes; (void)n_in; (void)out_size;
  const float* hid = (const float*)d_in[0];
  const float* enc = (const float*)d_in[1];
  float* out = (float*)d_out;

  const size_t encN = (size_t)NB_ * TS_ * DH_;
  const bool ws16 = (ws_size >= encN * sizeof(_Float16));

  dim3 grid(NB_ * (TQ_ / QB_), 1, 1);   // 1024 WGs of 1024 threads
  dim3 block(NT_, 1, 1);

  if (ws16) {
    _Float16* encH = (_Float16*)d_ws;
    convert_f32_f16<<<dim3((unsigned)(encN / 8 / 256)), dim3(256), 0, stream>>>(enc, encH);
    attn_v15<true><<<grid, block, 0, stream>>>(hid, enc, encH, out);
  } else {
    attn_v15<false><<<grid, block, 0, stream>>>(hid, enc, nullptr, out);
  }
}

// Round 16
// 755.189 us; speedup vs baseline: 1.6119x; 1.2323x over previous
//
#include <hip/hip_runtime.h>

#define NB_ 16
#define TQ_ 2048
#define TS_ 2048
#define DH_ 1024
#define QB_ 32
#define SB_ 256
#define NT_ 512
#define VTS_ 80   // Vt row stride in bytes (padded 64->80: conflict-free b128 reads)

typedef _Float16 f16x8 __attribute__((ext_vector_type(8)));
typedef _Float16 f16x4 __attribute__((ext_vector_type(4)));
typedef float f32x4 __attribute__((ext_vector_type(4)));

// LDS-domain barrier: does NOT drain vmcnt; in-flight global loads survive.
#define LDS_BARRIER() asm volatile("s_waitcnt lgkmcnt(0)\n\ts_barrier" ::: "memory")

__device__ inline uint32_t pack_h2(float a, float b) {
  union { _Float16 h[2]; uint32_t u; } c;
  c.h[0] = (_Float16)a; c.h[1] = (_Float16)b;
  return c.u;
}

__global__ void convert_f32_f16(const float* __restrict__ src, _Float16* __restrict__ dst) {
  size_t i = ((size_t)blockIdx.x * blockDim.x + threadIdx.x) * 8;
  float4 v0 = *(const float4*)(src + i);
  float4 v1 = *(const float4*)(src + i + 4);
  f16x8 o;
  o[0] = (_Float16)v0.x; o[1] = (_Float16)v0.y; o[2] = (_Float16)v0.z; o[3] = (_Float16)v0.w;
  o[4] = (_Float16)v1.x; o[5] = (_Float16)v1.y; o[6] = (_Float16)v1.z; o[7] = (_Float16)v1.w;
  *(f16x8*)(dst + i) = o;
}

__device__ inline f16x8 cvt8(const float* __restrict__ fp) {
  float4 a = *(const float4*)fp;
  float4 b = *(const float4*)(fp + 4);
  f16x8 t;
  t[0] = (_Float16)a.x; t[1] = (_Float16)a.y; t[2] = (_Float16)a.z; t[3] = (_Float16)a.w;
  t[4] = (_Float16)b.x; t[5] = (_Float16)b.y; t[6] = (_Float16)b.z; t[7] = (_Float16)b.w;
  return t;
}

template<bool WS16>
__device__ inline f16x8 ld8(const _Float16* __restrict__ hp, const float* __restrict__ fp, size_t idx) {
  if constexpr (WS16) return *(const f16x8*)(hp + idx);
  else return cvt8(fp + idx);
}

// LDS layout (bytes), total 156544 (<160 KiB, 1 WG/CU; v8-proven size):
//   q_base : 0      .. 65536   Q [32 q][1024 d] f16, byte=(q*2048+d*2)^((q&7)<<4)  [v12-verified]
//   s_lds  : 65536  .. 98816   S f32 [32 q][260]                                   [v12-verified]
//   p_base : 98816  .. 115200  P [32 q][256 s] f16, byte=(q*512+s*2)^((q&7)<<4)    [v12-verified]
//   vt     : 115200 .. 156160  8 x 5120 per-wave V-transpose [64 h][32 s], stride 80
//            byte = (h*80 + s*2) ^ (((h>>3)&7)<<4)   [writes 2-way free, reads conflict-free]
//   m/l/c  : 156160 .. 156544  softmax state
template<bool WS16>
__global__ __launch_bounds__(NT_, 2)
void attn_v16(const float* __restrict__ hid,
              const float* __restrict__ enc,
              const _Float16* __restrict__ encH,
              float* __restrict__ out) {
  __shared__ __attribute__((aligned(16))) char smem[156544];
  char*  const q_base = smem;
  float* const s_lds  = (float*)(smem + 65536);
  char*  const p_base = smem + 98816;
  char*  const vt_all = smem + 115200;
  float* const m_lds  = (float*)(smem + 156160);
  float* const l_lds  = m_lds + 32;
  float* const c_lds  = m_lds + 64;

  const int tid  = threadIdx.x;
  const int lane = tid & 63;
  const int wid  = tid >> 6;
  const int arow = lane & 15;
  const int agrp = lane >> 4;

  // XCD-affine: XCD x sweeps all 64 q-tiles of batch x, then batch x+8.
  const int bi  = blockIdx.x;
  const int x   = bi & 7;
  const int idx = bi >> 3;
  const int b   = x + 8 * (idx >> 6);
  const int q0  = (idx & 63) * QB_;

  const int hw = wid;  // PV h-chunk (128 wide); QK^T s-chunk = wid*32

  if (tid < 32) { m_lds[tid] = -__builtin_inff(); l_lds[tid] = 0.0f; }

  // ---- stage Q (32 x 1024) fp32 -> f16 into LDS, swizzled (v12-verified) ----
  {
    const float* qsrc = hid + ((size_t)b * TQ_ + q0) * DH_;
    #pragma unroll
    for (int k = 0; k < 16; ++k) {
      int i = tid + k * NT_;
      int q = i >> 8;
      int h = (i & 255) * 4;
      float4 v = *(const float4*)(qsrc + (size_t)q * DH_ + h);
      int byte = (q * 2048 + h * 2) ^ ((q & 7) << 4);
      *(uint32_t*)(q_base + byte)     = pack_h2(v.x, v.y);
      *(uint32_t*)(q_base + byte + 4) = pack_h2(v.z, v.w);
    }
  }
  __syncthreads();

  f32x4 o_acc[2][8];   // [m][n] over 128 h  (64 AGPR persistent)
  #pragma unroll
  for (int m = 0; m < 2; ++m)
    #pragma unroll
    for (int n = 0; n < 8; ++n)
      o_acc[m][n] = {};

  char* const vt = vt_all + wid * 5120;
  const size_t enc_b = (size_t)b * TS_ * DH_;
  const int c8 = (lane & 7) * 8;        // V staging h-octet (within 64)
  const int d2 = (lane >> 3) * 2;       // V staging s-pair base

  for (int st = 0; st < TS_ / SB_; ++st) {
    const int s0 = st * SB_;

    // ================= QK^T (v12-verified): full-d S[32q][32s], s-chunk = wid*32 =================
    f32x4 sacc[2][2] = {{{}, {}}, {{}, {}}};
    {
      const size_t krow = enc_b + (size_t)(s0 + wid * 32 + arow) * DH_;
      #pragma unroll
      for (int kf = 0; kf < 32; ++kf) {
        const int d = kf * 32 + agrp * 8;
        f16x8 bf0 = ld8<WS16>(encH, enc, krow + d);
        f16x8 bf1 = ld8<WS16>(encH, enc, krow + (size_t)16 * DH_ + d);
        f16x8 af0 = *(const f16x8*)(q_base + ((arow * 2048 + d * 2) ^ ((arow & 7) << 4)));
        f16x8 af1 = *(const f16x8*)(q_base + (((16 + arow) * 2048 + d * 2) ^ ((arow & 7) << 4)));
        sacc[0][0] = __builtin_amdgcn_mfma_f32_16x16x32_f16(af0, bf0, sacc[0][0], 0, 0, 0);
        sacc[0][1] = __builtin_amdgcn_mfma_f32_16x16x32_f16(af0, bf1, sacc[0][1], 0, 0, 0);
        sacc[1][0] = __builtin_amdgcn_mfma_f32_16x16x32_f16(af1, bf0, sacc[1][0], 0, 0, 0);
        sacc[1][1] = __builtin_amdgcn_mfma_f32_16x16x32_f16(af1, bf1, sacc[1][1], 0, 0, 0);
      }
    }

    // ---- issue PV pass-0 V loads (fly across both LDS barriers) ----
    f16x8 stgA[2][2], stgB[2][2];
    #pragma unroll
    for (int it = 0; it < 2; ++it) {
      size_t base = enc_b + (size_t)(s0 + it * 16 + d2) * DH_ + hw * 128 + c8;
      stgA[it][0] = ld8<WS16>(encH, enc, base);
      stgA[it][1] = ld8<WS16>(encH, enc, base + DH_);
    }

    // write S tile (single writer per element)
    {
      const int sc = wid * 32 + arow;
      #pragma unroll
      for (int m = 0; m < 2; ++m)
        #pragma unroll
        for (int n = 0; n < 2; ++n)
          #pragma unroll
          for (int i2 = 0; i2 < 4; ++i2)
            s_lds[(m * 16 + agrp * 4 + i2) * 260 + sc + n * 16] = sacc[m][n][i2];
    }

    LDS_BARRIER();  // b1: S complete (V loads stay in flight)

    // ================= online softmax over [32 q][256 s] (v12-verified) =================
    {
      int q = tid >> 4, sq = tid & 15;
      const float* bp = s_lds + q * 260 + sq * 16;
      f32x4 v0 = *(const f32x4*)bp;
      f32x4 v1 = *(const f32x4*)(bp + 4);
      f32x4 v2 = *(const f32x4*)(bp + 8);
      f32x4 v3 = *(const f32x4*)(bp + 12);
      f32x4 vm = v0;
      #pragma unroll
      for (int j = 0; j < 4; ++j) { vm[j] = fmaxf(fmaxf(v0[j], v1[j]), fmaxf(v2[j], v3[j])); }
      float mx = fmaxf(fmaxf(vm[0], vm[1]), fmaxf(vm[2], vm[3]));
      #pragma unroll
      for (int o = 8; o; o >>= 1) mx = fmaxf(mx, __shfl_xor(mx, o));
      float mprev = m_lds[q];
      float mnew  = fmaxf(mprev, mx);
      float p[16], ps = 0.0f;
      #pragma unroll
      for (int j = 0; j < 4; ++j) {
        p[j]      = __expf(v0[j] - mnew);
        p[4 + j]  = __expf(v1[j] - mnew);
        p[8 + j]  = __expf(v2[j] - mnew);
        p[12 + j] = __expf(v3[j] - mnew);
      }
      #pragma unroll
      for (int j = 0; j < 16; ++j) ps += p[j];
      #pragma unroll
      for (int o = 8; o; o >>= 1) ps += __shfl_xor(ps, o);
      if (sq == 0) {
        float cf = __expf(mprev - mnew);
        m_lds[q] = mnew;
        l_lds[q] = l_lds[q] * cf + ps;
        c_lds[q] = cf;
      }
      // two b128 writes (16-B blocks are XOR-uniform)
      #pragma unroll
      for (int g2 = 0; g2 < 2; ++g2) {
        f16x8 pw;
        #pragma unroll
        for (int j = 0; j < 8; ++j) pw[j] = (_Float16)p[g2 * 8 + j];
        *(f16x8*)(p_base + ((q * 512 + sq * 32 + g2 * 16) ^ ((q & 7) << 4))) = pw;
      }
    }

    LDS_BARRIER();  // b2: P + m/l/c complete

    // ---- rescale O ----
    #pragma unroll
    for (int m = 0; m < 2; ++m)
      #pragma unroll
      for (int i2 = 0; i2 < 4; ++i2) {
        float cf = c_lds[m * 16 + agrp * 4 + i2];
        #pragma unroll
        for (int n = 0; n < 8; ++n) o_acc[m][n][i2] *= cf;
      }

    // ================= PV: 16 passes (h-round r = pass>>3, s-phase sp = pass&7) =================
    #pragma unroll
    for (int pass = 0; pass < 16; ++pass) {
      const int r  = pass >> 3, sp = pass & 7;
      const bool useA = (pass & 1) == 0;
      // write Vt (wave-private, DS in-order, no barrier); stride-80 layout
      #pragma unroll
      for (int it = 0; it < 2; ++it) {
        int sl = it * 16 + d2;
        #pragma unroll
        for (int jj = 0; jj < 8; ++jj) {
          int hl = c8 + jj;
          union { _Float16 h[2]; uint32_t u; } pk;
          pk.h[0] = useA ? stgA[it][0][jj] : stgB[it][0][jj];
          pk.h[1] = useA ? stgA[it][1][jj] : stgB[it][1][jj];
          *(uint32_t*)(vt + ((hl * VTS_ + sl * 2) ^ (((hl >> 3) & 7) << 4))) = pk.u;
        }
      }
      // issue next pass's V loads into the other buffer
      if (pass < 15) {
        const int rn = (pass + 1) >> 3, spn = (pass + 1) & 7;
        #pragma unroll
        for (int it = 0; it < 2; ++it) {
          size_t base = enc_b + (size_t)(s0 + spn * 32 + it * 16 + d2) * DH_
                        + hw * 128 + rn * 64 + c8;
          if (useA) {
            stgB[it][0] = ld8<WS16>(encH, enc, base);
            stgB[it][1] = ld8<WS16>(encH, enc, base + DH_);
          } else {
            stgA[it][0] = ld8<WS16>(encH, enc, base);
            stgA[it][1] = ld8<WS16>(encH, enc, base + DH_);
          }
        }
      }
      // P A-frags for this s-phase
      f16x8 paf0 = *(const f16x8*)(p_base +
          ((arow * 512 + sp * 64 + agrp * 16) ^ ((arow & 7) << 4)));
      f16x8 paf1 = *(const f16x8*)(p_base +
          (((16 + arow) * 512 + sp * 64 + agrp * 16) ^ ((arow & 7) << 4)));
      __builtin_amdgcn_s_setprio(1);
      #pragma unroll
      for (int n = 0; n < 4; ++n) {
        int hl = n * 16 + arow;
        f16x8 bv = *(const f16x8*)(vt + ((hl * VTS_ + agrp * 16) ^ (((hl >> 3) & 7) << 4)));
        o_acc[0][r * 4 + n] = __builtin_amdgcn_mfma_f32_16x16x32_f16(paf0, bv, o_acc[0][r * 4 + n], 0, 0, 0);
        o_acc[1][r * 4 + n] = __builtin_amdgcn_mfma_f32_16x16x32_f16(paf1, bv, o_acc[1][r * 4 + n], 0, 0, 0);
      }
      __builtin_amdgcn_s_setprio(0);
    }
  }

  // ================= epilogue: O / l =================
  #pragma unroll
  for (int m = 0; m < 2; ++m) {
    #pragma unroll
    for (int i2 = 0; i2 < 4; ++i2) {
      int qr = m * 16 + agrp * 4 + i2;
      float inv = 1.0f / l_lds[qr];
      #pragma unroll
      for (int n = 0; n < 8; ++n) {
        out[((size_t)(b * TQ_ + q0 + qr)) * DH_ + hw * 128 + (n >> 2) * 64 + (n & 3) * 16 + arow] =
            o_acc[m][n][i2] * inv;
      }
    }
  }
}

extern "C" void kernel_launch(void* const* d_in, const int* in_sizes, int n_in,
                              void* d_out, int out_size, void* d_ws, size_t ws_size,
                              hipStream_t stream) {
  (void)in_sizes; (void)n_in; (void)out_size;
  const float* hid = (const float*)d_in[0];
  const float* enc = (const float*)d_in[1];
  float* out = (float*)d_out;

  const size_t encN = (size_t)NB_ * TS_ * DH_;
  const bool ws16 = (ws_size >= encN * sizeof(_Float16));

  dim3 grid(NB_ * (TQ_ / QB_), 1, 1);
  dim3 block(NT_, 1, 1);

  if (ws16) {
    _Float16* encH = (_Float16*)d_ws;
    convert_f32_f16<<<dim3((unsigned)(encN / 8 / 256)), dim3(256), 0, stream>>>(enc, encH);
    attn_v16<true><<<grid, block, 0, stream>>>(hid, enc, encH, out);
  } else {
    attn_v16<false><<<grid, block, 0, stream>>>(hid, enc, nullptr, out);
  }
}